// Round 10
// baseline (1720.411 us; speedup 1.0000x reference)
//
#include <hip/hip_runtime.h>
#include <hip/hip_bf16.h>

#define NN 50000
#define EE 100000
#define BB 2000
#define DIM 64
#define NF 14
#define EF 4
#define HID 128
#define EPAD 100096   // 391 * 256
#define NBLK 391
#define GSZ (NBLK * 256)

typedef __attribute__((ext_vector_type(8))) _Float16 half8;   // 4 VGPRs
typedef __attribute__((ext_vector_type(4))) _Float16 half4;
typedef __attribute__((ext_vector_type(4))) float floatx4;    // MFMA C/D 16x16

struct MegaP {
    const float* x; const float* ea; const int* ei;
    const float* l0w; const float* l0b;
    const float* w1; const float* b1;
    const float* w2; const float* b2;
    const float* root; const float* cb;
    const float* gwih; const float* gwhh; const float* gbih; const float* gbhh;
    const float* lih; const float* lhh; const float* lbih; const float* lbhh;
    const float* l1; const float* l1b; const float* l2w; const float* l2b;
    float* hv; float* agg; float* xsum; float* deg;
    float* lihT; float* lhhT; float* l1T; float* fbias;
    _Float16* he16; _Float16* W2rT; _Float16* W1h; _Float16* W2h;
    int* bar;
    float* out;
};

// ---- manual grid barrier: all NBLK blocks are co-resident (LDS caps occupancy at
// 2 blocks/CU -> 512 slots >= 391), so spin-wait is safe. Device-scope acq/rel. ----
__device__ __forceinline__ void gbar(int* bar) {
    __syncthreads();
    if (threadIdx.x == 0) {
        __threadfence();
        int gen = __hip_atomic_load(&bar[1], __ATOMIC_RELAXED, __HIP_MEMORY_SCOPE_AGENT);
        int prev = __hip_atomic_fetch_add(&bar[0], 1, __ATOMIC_ACQ_REL, __HIP_MEMORY_SCOPE_AGENT);
        if (prev == NBLK - 1) {
            __hip_atomic_store(&bar[0], 0, __ATOMIC_RELAXED, __HIP_MEMORY_SCOPE_AGENT);
            __hip_atomic_store(&bar[1], gen + 1, __ATOMIC_RELEASE, __HIP_MEMORY_SCOPE_AGENT);
        } else {
            while (__hip_atomic_load(&bar[1], __ATOMIC_ACQUIRE, __HIP_MEMORY_SCOPE_AGENT) == gen)
                __builtin_amdgcn_s_sleep(1);
        }
        __threadfence();
    }
    __syncthreads();
}

// ---------------- msg phase (round-5 body): one 256-edge tile; adds deg on it0 ----------------
__device__ __forceinline__ void msg_body(const MegaP& P, char* smem, int blk, bool it0) {
    _Float16* sB  = (_Float16*)smem;              // 2 x 8192 halves = 32768 B
    _Float16* sXs = (_Float16*)(smem + 32768);    // 256*72 halves = 36864 B
    int* sDst     = (int*)(smem + 69632);         // 1024 B
    const int t = threadIdx.x;
    const int eb = blk * 256;
    const int lane = t & 63, w = t >> 6;
    const int col = lane & 15, quad = lane >> 4;

    {
        int e = eb + t;
        sDst[t] = (e < EE) ? P.ei[EE + e] : 0;
        if (it0 && e < EE) atomicAdd(&P.deg[sDst[t]], 1.0f);
    }
    #pragma unroll 4
    for (int rep = 0; rep < 16; rep++) {
        int idx = rep * 256 + t;
        int el = idx >> 4, d4 = idx & 15;
        int e = eb + el;
        float4 v = {0.f, 0.f, 0.f, 0.f};
        if (e < EE) {
            int src = P.ei[e];
            v = *(const float4*)(P.hv + (size_t)src * 64 + d4 * 4);
        }
        half4 h4 = {(_Float16)v.x, (_Float16)v.y, (_Float16)v.z, (_Float16)v.w};
        *(half4*)&sXs[el * 72 + d4 * 4] = h4;
    }

    half8 heReg[4][4];
    #pragma unroll
    for (int mt = 0; mt < 4; mt++) {
        int row = eb + w * 64 + mt * 16 + col;
        #pragma unroll
        for (int p = 0; p < 4; p++)
            heReg[mt][p] = *(const half8*)(P.he16 + (size_t)row * 128 + p * 32 + quad * 8);
    }

    floatx4 Cacc[4][4];
    #pragma unroll
    for (int mt = 0; mt < 4; mt++)
        #pragma unroll
        for (int nt = 0; nt < 4; nt++)
            Cacc[mt][nt] = (floatx4){0.f, 0.f, 0.f, 0.f};

    const _Float16* gsrc = P.W2rT + (size_t)(w * 16 + col) * 8192 + quad * 8;
    half8 pre[4];
    {
        #pragma unroll
        for (int rep = 0; rep < 4; rep++)
            pre[rep] = *(const half8*)(gsrc + rep * 32);
        #pragma unroll
        for (int rep = 0; rep < 4; rep++)
            *(half8*)&sB[((w * 4 + rep) * 64 + lane) * 8] = pre[rep];
    }
    __syncthreads();

    #pragma unroll 1
    for (int i4 = 0; i4 < 16; i4++) {
        half4 xsv[4];
        #pragma unroll
        for (int mt = 0; mt < 4; mt++)
            xsv[mt] = *(const half4*)&sXs[(w * 64 + mt * 16 + col) * 72 + i4 * 4];
        #pragma unroll
        for (int ii = 0; ii < 4; ii++) {
            const int i = i4 * 4 + ii;
            const int buf = i & 1;
            if (i < 63) {
                #pragma unroll
                for (int rep = 0; rep < 4; rep++)
                    pre[rep] = *(const half8*)(gsrc + (size_t)(i + 1) * 128 + rep * 32);
            }
            #pragma unroll
            for (int ks = 0; ks < 4; ks++) {
                half8 bfr[4];
                #pragma unroll
                for (int nt = 0; nt < 4; nt++)
                    bfr[nt] = *(const half8*)&sB[(size_t)buf * 8192 + ((nt * 4 + ks) * 64 + lane) * 8];
                #pragma unroll
                for (int mt = 0; mt < 4; mt++) {
                    half8 afr = heReg[mt][ks] * xsv[mt][ii];
                    #pragma unroll
                    for (int nt = 0; nt < 4; nt++)
                        Cacc[mt][nt] = __builtin_amdgcn_mfma_f32_16x16x32_f16(afr, bfr[nt], Cacc[mt][nt], 0, 0, 0);
                }
            }
            if (i < 63) {
                #pragma unroll
                for (int rep = 0; rep < 4; rep++)
                    *(half8*)&sB[(size_t)(buf ^ 1) * 8192 + ((w * 4 + rep) * 64 + lane) * 8] = pre[rep];
            }
            __syncthreads();
        }
    }

    #pragma unroll
    for (int mt = 0; mt < 4; mt++) {
        #pragma unroll
        for (int r = 0; r < 4; r++) {
            int el = w * 64 + mt * 16 + quad * 4 + r;
            if (eb + el < EE) {
                float* ap = P.agg + (size_t)sDst[el] * 64 + col;
                #pragma unroll
                for (int nt = 0; nt < 4; nt++)
                    atomicAdd(ap + nt * 16, Cacc[mt][nt][r]);
            }
        }
    }
    #pragma unroll 4
    for (int rep = 0; rep < 64; rep++) {
        int idx = rep * 256 + t;
        int el = idx >> 6, d = idx & 63;
        if (eb + el < EE)
            atomicAdd(&P.xsum[(size_t)sDst[el] * 64 + d], (float)sXs[el * 72 + d]);
    }
}

// ---------------- node phase (round-5 body incl. OWN-RANGE re-zero): 64-node tile ----------------
__device__ __forceinline__ void node_body(const MegaP& P, char* smem, int nb) {
    _Float16* sA1 = (_Float16*)smem;              // 64*136 halves
    _Float16* sA2 = (_Float16*)(smem + 17408);
    float* sH     = (float*)(smem + 34816);       // 64*68 floats
    float* sAgg   = (float*)(smem + 52224);
    const int t = threadIdx.x;
    __syncthreads();   // smem reuse guard
    const int n = t >> 2, part = t & 3;
    {
        int gn = nb + n;
        bool valid = gn < NN;
        float inv = 1.f;
        if (valid) inv = 1.f / fmaxf(P.deg[gn], 1.f);
        #pragma unroll
        for (int c4 = 0; c4 < 4; c4++) {
            int d0 = part * 16 + c4 * 4;
            float4 hvv = {0.f, 0.f, 0.f, 0.f}, agv = {0.f, 0.f, 0.f, 0.f}, xsv = {0.f, 0.f, 0.f, 0.f};
            if (valid) {
                hvv = *(const float4*)(P.hv + (size_t)gn * 64 + d0);
                agv = *(const float4*)(P.agg + (size_t)gn * 64 + d0);
                xsv = *(const float4*)(P.xsum + (size_t)gn * 64 + d0);
            }
            agv.x *= inv; agv.y *= inv; agv.z *= inv; agv.w *= inv;
            xsv.x *= inv; xsv.y *= inv; xsv.z *= inv; xsv.w *= inv;
            half4 hvh = {(_Float16)hvv.x, (_Float16)hvv.y, (_Float16)hvv.z, (_Float16)hvv.w};
            half4 xsh = {(_Float16)xsv.x, (_Float16)xsv.y, (_Float16)xsv.z, (_Float16)xsv.w};
            *(half4*)&sA1[n * 136 + d0] = hvh;
            *(half4*)&sA1[n * 136 + 64 + d0] = xsh;
            *(half4*)&sA2[n * 136 + 64 + d0] = hvh;
            *(float4*)&sH[n * 68 + d0] = hvv;
            *(float4*)&sAgg[n * 68 + d0] = agv;
        }
        if (valid) {   // re-zero OWN range only (no cross-block race)
            float4 z = {0.f, 0.f, 0.f, 0.f};
            #pragma unroll
            for (int c4 = 0; c4 < 4; c4++) {
                int d0 = part * 16 + c4 * 4;
                *(float4*)(P.agg + (size_t)gn * 64 + d0) = z;
                *(float4*)(P.xsum + (size_t)gn * 64 + d0) = z;
            }
        }
    }
    __syncthreads();

    const int lane = t & 63, w = t >> 6;
    const int col = lane & 15, quad = lane >> 4;

    floatx4 C1[4];
    #pragma unroll
    for (int nt = 0; nt < 4; nt++) {
        float b = P.cb[nt * 16 + col];
        C1[nt] = (floatx4){b, b, b, b};
    }
    #pragma unroll
    for (int ks = 0; ks < 4; ks++) {
        half8 a = *(const half8*)&sA1[(w * 16 + col) * 136 + ks * 32 + quad * 8];
        #pragma unroll
        for (int nt = 0; nt < 4; nt++) {
            half8 bfr = *(const half8*)(P.W1h + (size_t)(nt * 16 + col) * 128 + ks * 32 + quad * 8);
            C1[nt] = __builtin_amdgcn_mfma_f32_16x16x32_f16(a, bfr, C1[nt], 0, 0, 0);
        }
    }
    #pragma unroll
    for (int nt = 0; nt < 4; nt++) {
        #pragma unroll
        for (int r = 0; r < 4; r++) {
            int node = w * 16 + quad * 4 + r;
            int j = nt * 16 + col;
            float m = fmaxf(C1[nt][r] + sAgg[node * 68 + j], 0.f);
            sA2[node * 136 + j] = (_Float16)m;
        }
    }
    __syncthreads();

    floatx4 C2[16];
    #pragma unroll
    for (int nt2 = 0; nt2 < 16; nt2++) {
        float b = P.fbias[nt2 * 16 + col];
        C2[nt2] = (floatx4){b, b, b, b};
    }
    #pragma unroll
    for (int ks = 0; ks < 4; ks++) {
        half8 a = *(const half8*)&sA2[(w * 16 + col) * 136 + ks * 32 + quad * 8];
        #pragma unroll
        for (int nt2 = 0; nt2 < 16; nt2++) {
            half8 bfr = *(const half8*)(P.W2h + (size_t)(nt2 * 16 + col) * 128 + ks * 32 + quad * 8);
            C2[nt2] = __builtin_amdgcn_mfma_f32_16x16x32_f16(a, bfr, C2[nt2], 0, 0, 0);
        }
    }
    float hnew[4][4];
    #pragma unroll
    for (int r = 0; r < 4; r++) {
        int node = w * 16 + quad * 4 + r;
        #pragma unroll
        for (int jt = 0; jt < 4; jt++) {
            int j = jt * 16 + col;
            float rr = 1.f / (1.f + expf(-C2[jt][r]));
            float zz = 1.f / (1.f + expf(-C2[4 + jt][r]));
            float ng = tanhf(C2[8 + jt][r] + rr * C2[12 + jt][r]);
            float hold = sH[node * 68 + j];
            hnew[r][jt] = (1.f - zz) * ng + zz * hold;
        }
    }
    __syncthreads();
    #pragma unroll
    for (int r = 0; r < 4; r++) {
        int node = w * 16 + quad * 4 + r;
        #pragma unroll
        for (int jt = 0; jt < 4; jt++)
            sH[node * 68 + jt * 16 + col] = hnew[r][jt];
    }
    __syncthreads();
    {
        int gn = nb + n;
        if (gn < NN) {
            #pragma unroll
            for (int c4 = 0; c4 < 4; c4++) {
                int d0 = part * 16 + c4 * 4;
                *(float4*)(P.hv + (size_t)gn * 64 + d0) = *(const float4*)&sH[n * 68 + d0];
            }
        }
    }
}

// ---------------- set2set + readout: one graph ----------------
__device__ __forceinline__ void set2set_body(const MegaP& P, char* smem, int g) {
    float* outS = (float*)smem;
    float* qs  = (float*)smem + 1632;
    float* qh  = (float*)smem + 1760;
    float* qc  = (float*)smem + 1824;
    float* gat = (float*)smem + 1888;
    float* ew  = (float*)smem + 2144;
    float* aw  = (float*)smem + 2176;
    float* red = (float*)smem + 2208;
    const int t = threadIdx.x;
    __syncthreads();
    for (int p = t; p < 25 * 64; p += 256) {
        int j = p >> 6, i = p & 63;
        outS[j * 65 + i] = P.hv[(size_t)(g * 25 + j) * 64 + i];
    }
    if (t < 128) qs[t] = 0.f;
    if (t < 64) { qh[t] = 0.f; qc[t] = 0.f; }
    __syncthreads();
    for (int it = 0; it < 3; it++) {
        float acc = P.lbih[t] + P.lbhh[t];
        for (int k = 0; k < 128; k++) acc += qs[k] * P.lihT[k * 256 + t];
        for (int k = 0; k < 64; k++) acc += qh[k] * P.lhhT[k * 256 + t];
        gat[t] = acc;
        __syncthreads();
        if (t < 64) {
            float ig = 1.f / (1.f + expf(-gat[t]));
            float fg = 1.f / (1.f + expf(-gat[64 + t]));
            float gg = tanhf(gat[128 + t]);
            float og = 1.f / (1.f + expf(-gat[192 + t]));
            float c = fg * qc[t] + ig * gg;
            qc[t] = c;
            qh[t] = og * tanhf(c);
        }
        __syncthreads();
        if (t < 25) {
            float e = 0.f;
            for (int i = 0; i < 64; i++) e += outS[t * 65 + i] * qh[i];
            ew[t] = e;
        }
        __syncthreads();
        if (t == 0) {
            float mx = ew[0];
            for (int j = 1; j < 25; j++) mx = fmaxf(mx, ew[j]);
            float s = 0.f;
            for (int j = 0; j < 25; j++) { float a = expf(ew[j] - mx); aw[j] = a; s += a; }
            float inv = 1.f / s;
            for (int j = 0; j < 25; j++) aw[j] *= inv;
        }
        __syncthreads();
        if (t < 64) {
            float r = 0.f;
            for (int j = 0; j < 25; j++) r += aw[j] * outS[j * 65 + t];
            qs[t] = qh[t];
            qs[64 + t] = r;
        }
        __syncthreads();
    }
    if (t < 64) {
        float y1 = P.l1b[t];
        for (int k = 0; k < 128; k++) y1 += qs[k] * P.l1T[k * 64 + t];
        y1 = fmaxf(y1, 0.f);
        red[t] = y1 * P.l2w[t];
    }
    __syncthreads();
    if (t == 0) {
        float y = P.l2b[0];
        for (int i = 0; i < 64; i++) y += red[i];
        P.out[g] = y;
    }
}

// ---------------- the whole model: one persistent kernel, manual grid barrier ----------------
__global__ __launch_bounds__(256, 2) void mega_kernel(MegaP P) {
    __shared__ __align__(16) char smem[70656];
    const int blk = blockIdx.x;
    const int t = threadIdx.x;
    const int gtid = blk * 256 + t;

    // ---- P0: zeros + weight prep + he16 + lin0 ----
    {
        float4 z4 = {0.f, 0.f, 0.f, 0.f};
        float4* agz = (float4*)P.agg;   // agg & xsum carved adjacent
        for (int i = gtid; i < (NN * 64 * 2) / 4; i += GSZ) agz[i] = z4;
        for (int i = gtid; i < NN; i += GSZ) P.deg[i] = 0.f;

        for (int i = gtid; i < 64 * 8192; i += GSZ) {
            int o = i >> 13, k = i & 8191, ii = k >> 7, h = k & 127;
            P.W2rT[i] = (_Float16)P.w2[(size_t)(ii * 64 + o) * 128 + h];
        }
        if (gtid < 256 * 128) { int j = gtid / 128, k = gtid % 128; P.lihT[k * 256 + j] = P.lih[gtid]; }
        if (gtid < 256 * 64)  { int j = gtid / 64, k = gtid % 64;  P.lhhT[k * 256 + j] = P.lhh[gtid]; }
        if (gtid < 64 * 128)  { int d = gtid / 128, k = gtid % 128; P.l1T[k * 64 + d] = P.l1[gtid]; }
        if (gtid < 64 * 128) {
            int n = gtid >> 7, k = gtid & 127;
            P.W1h[gtid] = (_Float16)(k < 64 ? P.root[k * 64 + n] : P.b2[(size_t)(k - 64) * 64 + n]);
        }
        if (gtid < 256 * 128) {
            int n2 = gtid >> 7, k = gtid & 127;
            int gg = n2 >> 6, j = n2 & 63;
            float v;
            if (gg == 0)      v = (k < 64) ? P.gwih[j * 64 + k]         : P.gwhh[j * 64 + (k - 64)];
            else if (gg == 1) v = (k < 64) ? P.gwih[(64 + j) * 64 + k]  : P.gwhh[(64 + j) * 64 + (k - 64)];
            else if (gg == 2) v = (k < 64) ? P.gwih[(128 + j) * 64 + k] : 0.f;
            else              v = (k < 64) ? 0.f                        : P.gwhh[(128 + j) * 64 + (k - 64)];
            P.W2h[gtid] = (_Float16)v;
        }
        if (gtid < 256) {
            int gg = gtid >> 6, j = gtid & 63;
            float v = (gg == 0) ? P.gbih[j] + P.gbhh[j]
                    : (gg == 1) ? P.gbih[64 + j] + P.gbhh[64 + j]
                    : (gg == 2) ? P.gbih[128 + j] : P.gbhh[128 + j];
            P.fbias[gtid] = v;
        }
        const int eb = blk * 256;
        for (int r = t; r < 256 * 128; r += 256) {
            int el = eb + (r >> 7), h = r & 127;
            float acc = 0.f;
            if (el < EE) {
                float4 a = *(const float4*)(P.ea + (size_t)el * 4);
                float4 wv = *(const float4*)(P.w1 + h * 4);
                acc = fmaxf(P.b1[h] + a.x * wv.x + a.y * wv.y + a.z * wv.z + a.w * wv.w, 0.f);
            }
            P.he16[(size_t)el * 128 + h] = (_Float16)acc;
        }
        for (int i = gtid; i < NN * 64; i += GSZ) {
            int n = i >> 6, d = i & 63;
            float acc = P.l0b[d];
            #pragma unroll
            for (int f = 0; f < NF; f++) acc += P.x[n * NF + f] * P.l0w[d * NF + f];
            P.hv[i] = fmaxf(acc, 0.f);
        }
    }
    gbar(P.bar);

    // ---- 3 message-passing + GRU iterations ----
    for (int it = 0; it < 3; it++) {
        msg_body(P, smem, blk, it == 0);
        gbar(P.bar);
        node_body(P, smem, blk * 64);
        node_body(P, smem, (blk + NBLK) * 64);
        gbar(P.bar);
    }

    // ---- Set2Set + readout ----
    for (int g = blk; g < BB; g += NBLK)
        set2set_body(P, smem, g);
}

extern "C" void kernel_launch(void* const* d_in, const int* in_sizes, int n_in,
                              void* d_out, int out_size, void* d_ws, size_t ws_size,
                              hipStream_t stream) {
    // ---- workspace carve ----
    char* base = (char*)d_ws;
    size_t off = 0;
    auto carve = [&](size_t bytes) -> void* {
        void* r = base + off;
        off = (off + bytes + 255) & ~(size_t)255;
        return r;
    };
    int*   bar  = (int*)carve(256);
    float* hv   = (float*)carve((size_t)NN * 64 * 4);
    float* agg  = (float*)carve((size_t)NN * 64 * 4);   // agg+xsum adjacent (zeroed together)
    float* xsum = (float*)carve((size_t)NN * 64 * 4);
    float* deg  = (float*)carve((size_t)NN * 4);
    float* lihT = (float*)carve(128 * 256 * 4);
    float* lhhT = (float*)carve(64 * 256 * 4);
    float* l1T  = (float*)carve(128 * 64 * 4);
    float* fbias = (float*)carve(256 * 4);
    _Float16* he16 = (_Float16*)carve((size_t)EPAD * 128 * 2);
    _Float16* W2rT = (_Float16*)carve((size_t)64 * 8192 * 2);
    _Float16* W1h  = (_Float16*)carve((size_t)64 * 128 * 2);
    _Float16* W2h  = (_Float16*)carve((size_t)256 * 128 * 2);

    MegaP p;
    p.x    = (const float*)d_in[0];
    p.ea   = (const float*)d_in[1];
    p.ei   = (const int*)  d_in[2];
    p.l0w  = (const float*)d_in[4];
    p.l0b  = (const float*)d_in[5];
    p.w1   = (const float*)d_in[6];
    p.b1   = (const float*)d_in[7];
    p.w2   = (const float*)d_in[8];
    p.b2   = (const float*)d_in[9];
    p.root = (const float*)d_in[10];
    p.cb   = (const float*)d_in[11];
    p.gwih = (const float*)d_in[12];
    p.gwhh = (const float*)d_in[13];
    p.gbih = (const float*)d_in[14];
    p.gbhh = (const float*)d_in[15];
    p.lih  = (const float*)d_in[16];
    p.lhh  = (const float*)d_in[17];
    p.lbih = (const float*)d_in[18];
    p.lbhh = (const float*)d_in[19];
    p.l1   = (const float*)d_in[20];
    p.l1b  = (const float*)d_in[21];
    p.l2w  = (const float*)d_in[22];
    p.l2b  = (const float*)d_in[23];
    p.hv = hv; p.agg = agg; p.xsum = xsum; p.deg = deg;
    p.lihT = lihT; p.lhhT = lhhT; p.l1T = l1T; p.fbias = fbias;
    p.he16 = he16; p.W2rT = W2rT; p.W1h = W1h; p.W2h = W2h;
    p.bar = bar;
    p.out = (float*)d_out;

    hipMemsetAsync(bar, 0, 256, stream);   // barrier counter + generation
    mega_kernel<<<NBLK, 256, 0, stream>>>(p);
}